// Round 8
// baseline (258.724 us; speedup 1.0000x reference)
//
#include <hip/hip_runtime.h>
#include <hip/hip_bf16.h>

// GNN forward: 3 layers of COO SpMM + gating, mean over layer embeddings.
// N=50000, E=800000, D=96.
//
// Round-8 = round-7 + per-row ELL sorted by column.
//  Rationale: SpMM sits at the ~3.2 TB/s random-line (L3->L2) ceiling with
//  ~0% L2 hits (ego 9.6 MB > 4 MB/XCD L2). With every row's entries sorted
//  by col, all co-resident blocks sweep columns low->high together, so the
//  instantaneous column window fits in L2 -> gather hits.
//  - setup (bin+convert) and spmm kernels are r7-identical.
//  - sort_kernel: thread-per-row LDS insertion sort (split col/val arrays,
//    stride 65 words -> conflict-free).

#define N_NODES 50000
#define N_EDGES 800000
#define EMB 96
#define C16 12                    // 16B bf16 chunks per row
#define LAYER_NUM 3
#define PAD 64                    // ELL slots per row
#define NCHUNK (N_NODES * C16)    // 600000
#define SORT_TPB 64

__device__ __forceinline__ float bflo(unsigned u) { return __uint_as_float(u << 16); }
__device__ __forceinline__ float bfhi(unsigned u) { return __uint_as_float(u & 0xffff0000u); }

__device__ __forceinline__ void fma_bf8(float* s, float v, const uint4& u) {
    s[0] = fmaf(v, bflo(u.x), s[0]);
    s[1] = fmaf(v, bfhi(u.x), s[1]);
    s[2] = fmaf(v, bflo(u.y), s[2]);
    s[3] = fmaf(v, bfhi(u.y), s[3]);
    s[4] = fmaf(v, bflo(u.z), s[4]);
    s[5] = fmaf(v, bfhi(u.z), s[5]);
    s[6] = fmaf(v, bflo(u.w), s[6]);
    s[7] = fmaf(v, bfhi(u.w), s[7]);
}

// RNE pack: a -> low 16, b -> high 16
__device__ __forceinline__ unsigned packbf(float a, float b) {
    unsigned ua = __float_as_uint(a);
    unsigned ub = __float_as_uint(b);
    ua = (ua + 0x7fffu + ((ua >> 16) & 1u)) >> 16;
    ub = (ub + 0x7fffu + ((ub >> 16) & 1u)) & 0xffff0000u;
    return ua | ub;
}

// Fused: X(fp32) -> Xb(bf16) convert  +  edge binning into ELL. (r7-identical)
__global__ void setup_kernel(const float4* __restrict__ X4,
                             uint4* __restrict__ Xb,
                             const int* __restrict__ rows,
                             const int* __restrict__ cols,
                             const float* __restrict__ vals,
                             int* __restrict__ cnt,
                             int2* __restrict__ ell) {
    int tid = blockIdx.x * blockDim.x + threadIdx.x;
    if (tid < NCHUNK) {
        float4 a = X4[tid * 2];
        float4 b = X4[tid * 2 + 1];
        uint4 o;
        o.x = packbf(a.x, a.y);
        o.y = packbf(a.z, a.w);
        o.z = packbf(b.x, b.y);
        o.w = packbf(b.z, b.w);
        Xb[tid] = o;
    }
    if (tid < N_EDGES) {
        int r = rows[tid];
        int slot = atomicAdd(&cnt[r], 1);
        if (slot < PAD) {
            int2 p;
            p.x = cols[tid];
            p.y = __float_as_int(vals[tid]);
            ell[r * PAD + slot] = p;
        }
    }
}

// Sort each row's ELL entries by col. One thread per row; per-thread LDS
// slice; split col/val arrays with stride 65 words (bank-conflict-free).
__global__ void sort_kernel(const int* __restrict__ cnt,
                            int2* __restrict__ ell) {
    __shared__ int scol[SORT_TPB * 65];
    __shared__ int sval[SORT_TPB * 65];
    int r = blockIdx.x * SORT_TPB + threadIdx.x;
    if (r >= N_NODES) return;
    int deg = cnt[r];
    if (deg > PAD) deg = PAD;
    int2* ep = ell + (size_t)r * PAD;
    int* c = scol + threadIdx.x * 65;
    int* v = sval + threadIdx.x * 65;
    for (int j = 0; j < deg; ++j) {
        int2 q = ep[j];
        c[j] = q.x;
        v[j] = q.y;
    }
    for (int i = 1; i < deg; ++i) {
        int key = c[i], pv = v[i];
        int k = i - 1;
        while (k >= 0 && c[k] > key) {
            c[k + 1] = c[k];
            v[k + 1] = v[k];
            --k;
        }
        c[k + 1] = key;
        v[k + 1] = pv;
    }
    for (int j = 0; j < deg; ++j) {
        int2 q;
        q.x = c[j];
        q.y = v[j];
        ep[j] = q;
    }
}

// One thread per (row, 16B chunk): 12 threads/row. (r7-identical)
// FIRST: ego_in is Xb, acc is write-only (acc = X + ego1).
// LAST: skip ego_out store, fold /4 mean via scale.
template <bool FIRST, bool LAST>
__global__ void spmm_fused_kernel(const uint4* __restrict__ ego_in,
                                  uint4* __restrict__ ego_out,
                                  const int* __restrict__ cnt,
                                  const int4* __restrict__ ell4,
                                  float4* __restrict__ acc,
                                  float scale) {
    int tid = blockIdx.x * blockDim.x + threadIdx.x;
    if (tid >= N_NODES * C16) return;
    int row = tid / C16;
    int ct  = tid % C16;

    int deg = cnt[row];
    if (deg > PAD) deg = PAD;
    const int4* ep = ell4 + row * (PAD / 2);

    // hoisted: independent of the gather chain
    int ib = row * C16 + ct;
    uint4 ea = ego_in[ib];
    int ia = row * (EMB / 4) + ct * 2;
    float4 a0, a1;
    if (!FIRST) {
        a0 = acc[ia];
        a1 = acc[ia + 1];
    }

    float s[8] = {0.f, 0.f, 0.f, 0.f, 0.f, 0.f, 0.f, 0.f};

    int j = 0;
    for (; j + 4 <= deg; j += 4) {
        int4 pA = ep[(j >> 1) + 0];
        int4 pB = ep[(j >> 1) + 1];
        uint4 x0 = ego_in[pA.x * C16 + ct];
        uint4 x1 = ego_in[pA.z * C16 + ct];
        uint4 x2 = ego_in[pB.x * C16 + ct];
        uint4 x3 = ego_in[pB.z * C16 + ct];
        fma_bf8(s, __int_as_float(pA.y), x0);
        fma_bf8(s, __int_as_float(pA.w), x1);
        fma_bf8(s, __int_as_float(pB.y), x2);
        fma_bf8(s, __int_as_float(pB.w), x3);
    }
    if (j + 2 <= deg) {
        int4 pA = ep[j >> 1];
        uint4 x0 = ego_in[pA.x * C16 + ct];
        uint4 x1 = ego_in[pA.z * C16 + ct];
        fma_bf8(s, __int_as_float(pA.y), x0);
        fma_bf8(s, __int_as_float(pA.w), x1);
        j += 2;
    }
    if (j < deg) {
        int2 p = ((const int2*)ell4)[row * PAD + j];
        uint4 x0 = ego_in[p.x * C16 + ct];
        fma_bf8(s, __int_as_float(p.y), x0);
    }

    float e0[8] = {bflo(ea.x), bfhi(ea.x), bflo(ea.y), bfhi(ea.y),
                   bflo(ea.z), bfhi(ea.z), bflo(ea.w), bfhi(ea.w)};
    float n0[8];
#pragma unroll
    for (int k = 0; k < 8; ++k) n0[k] = fmaf(s[k], e0[k], s[k]);   // s*(1+e)

    if (!LAST) {
        uint4 oa;
        oa.x = packbf(n0[0], n0[1]); oa.y = packbf(n0[2], n0[3]);
        oa.z = packbf(n0[4], n0[5]); oa.w = packbf(n0[6], n0[7]);
        ego_out[ib] = oa;
    }

    if (FIRST) {
        a0 = make_float4(e0[0] + n0[0], e0[1] + n0[1], e0[2] + n0[2], e0[3] + n0[3]);
        a1 = make_float4(e0[4] + n0[4], e0[5] + n0[5], e0[6] + n0[6], e0[7] + n0[7]);
    } else {
        a0.x = (a0.x + n0[0]) * scale; a0.y = (a0.y + n0[1]) * scale;
        a0.z = (a0.z + n0[2]) * scale; a0.w = (a0.w + n0[3]) * scale;
        a1.x = (a1.x + n0[4]) * scale; a1.y = (a1.y + n0[5]) * scale;
        a1.z = (a1.z + n0[6]) * scale; a1.w = (a1.w + n0[7]) * scale;
    }
    acc[ia]     = a0;
    acc[ia + 1] = a1;
}

extern "C" void kernel_launch(void* const* d_in, const int* in_sizes, int n_in,
                              void* d_out, int out_size, void* d_ws, size_t ws_size,
                              hipStream_t stream) {
    const float* X    = (const float*)d_in[0];
    const float* vals = (const float*)d_in[1];
    const int*   rows = (const int*)d_in[2];
    const int*   cols = (const int*)d_in[3];

    const size_t nodeb_bytes = (size_t)NCHUNK * sizeof(uint4);       // 9.6 MB
    const size_t ell_bytes   = (size_t)N_NODES * PAD * sizeof(int2); // 25.6 MB
    const size_t cnt_bytes   = (size_t)N_NODES * sizeof(int);

    float* acc = (float*)d_out;

    char* w = (char*)d_ws;
    uint4* Xb    = (uint4*)w;  w += nodeb_bytes;
    uint4* ego_a = (uint4*)w;  w += nodeb_bytes;
    uint4* ego_b = (uint4*)w;  w += nodeb_bytes;
    int2*  ell   = (int2*)w;   w += ell_bytes;
    int*   cnt   = (int*)w;

    hipMemsetAsync(cnt, 0, cnt_bytes, stream);
    setup_kernel<<<(N_EDGES + 255) / 256, 256, 0, stream>>>(
        (const float4*)X, Xb, rows, cols, vals, cnt, ell);

    sort_kernel<<<(N_NODES + SORT_TPB - 1) / SORT_TPB, SORT_TPB, 0, stream>>>(cnt, ell);

    const int blocks = (N_NODES * C16 + 255) / 256;
    const float last_scale = 1.0f / (LAYER_NUM + 1);

    spmm_fused_kernel<true, false><<<blocks, 256, 0, stream>>>(
        Xb, ego_a, cnt, (const int4*)ell, (float4*)acc, 1.0f);
    spmm_fused_kernel<false, false><<<blocks, 256, 0, stream>>>(
        ego_a, ego_b, cnt, (const int4*)ell, (float4*)acc, 1.0f);
    spmm_fused_kernel<false, true><<<blocks, 256, 0, stream>>>(
        ego_b, ego_a, cnt, (const int4*)ell, (float4*)acc, last_scale);
}

// Round 9
// 239.196 us; speedup vs baseline: 1.0816x; 1.0816x over previous
//
#include <hip/hip_runtime.h>
#include <hip/hip_bf16.h>

// GNN forward: 3 layers of COO SpMM + gating, mean over layer embeddings.
// N=50000, E=800000, D=96.
//
// Round-9 = round-7 (best: 217 us) + non-temporal hints on all single-use
// streams. Rationale: SpMM's gather set (ego, 9.6 MB) fights for 4 MB/XCD L2
// against ~48 MB/layer of streaming traffic (ELL reads, acc RMW, ego_out
// stores). nt loads/stores keep those streams out of L2, reserving it for
// gathers. Setup's ELL scatter also goes nt (may skip write-allocate).
//  - 12 threads/row SpMM (lane-contiguous stores), flat ELL PAD=64,
//    4-neighbor unroll, hoisted self/acc loads, last layer skips ego_out.
//  - bf16 features (fp32 accum), X->bf16 fused into setup.

#define N_NODES 50000
#define N_EDGES 800000
#define EMB 96
#define C16 12                    // 16B bf16 chunks per row
#define LAYER_NUM 3
#define PAD 64                    // ELL slots per row
#define NCHUNK (N_NODES * C16)    // 600000

typedef int   __attribute__((ext_vector_type(4))) ivec4;
typedef int   __attribute__((ext_vector_type(2))) ivec2;
typedef unsigned int __attribute__((ext_vector_type(4))) uvec4;
typedef float __attribute__((ext_vector_type(4))) fvec4;

__device__ __forceinline__ int4 ntload_i4(const int4* p) {
    ivec4 t = __builtin_nontemporal_load((const ivec4*)p);
    int4 r; r.x = t.x; r.y = t.y; r.z = t.z; r.w = t.w; return r;
}
__device__ __forceinline__ int2 ntload_i2(const int2* p) {
    ivec2 t = __builtin_nontemporal_load((const ivec2*)p);
    int2 r; r.x = t.x; r.y = t.y; return r;
}
__device__ __forceinline__ float4 ntload_f4(const float4* p) {
    fvec4 t = __builtin_nontemporal_load((const fvec4*)p);
    float4 r; r.x = t.x; r.y = t.y; r.z = t.z; r.w = t.w; return r;
}
__device__ __forceinline__ float ntload_f(const float* p) {
    return __builtin_nontemporal_load(p);
}
__device__ __forceinline__ int ntload_i(const int* p) {
    return __builtin_nontemporal_load(p);
}
__device__ __forceinline__ void ntstore_u4(uint4* p, uint4 v) {
    uvec4 t; t.x = v.x; t.y = v.y; t.z = v.z; t.w = v.w;
    __builtin_nontemporal_store(t, (uvec4*)p);
}
__device__ __forceinline__ void ntstore_f4(float4* p, float4 v) {
    fvec4 t; t.x = v.x; t.y = v.y; t.z = v.z; t.w = v.w;
    __builtin_nontemporal_store(t, (fvec4*)p);
}
__device__ __forceinline__ void ntstore_i2(int2* p, int2 v) {
    ivec2 t; t.x = v.x; t.y = v.y;
    __builtin_nontemporal_store(t, (ivec2*)p);
}

__device__ __forceinline__ float bflo(unsigned u) { return __uint_as_float(u << 16); }
__device__ __forceinline__ float bfhi(unsigned u) { return __uint_as_float(u & 0xffff0000u); }

__device__ __forceinline__ void fma_bf8(float* s, float v, const uint4& u) {
    s[0] = fmaf(v, bflo(u.x), s[0]);
    s[1] = fmaf(v, bfhi(u.x), s[1]);
    s[2] = fmaf(v, bflo(u.y), s[2]);
    s[3] = fmaf(v, bfhi(u.y), s[3]);
    s[4] = fmaf(v, bflo(u.z), s[4]);
    s[5] = fmaf(v, bfhi(u.z), s[5]);
    s[6] = fmaf(v, bflo(u.w), s[6]);
    s[7] = fmaf(v, bfhi(u.w), s[7]);
}

// RNE pack: a -> low 16, b -> high 16
__device__ __forceinline__ unsigned packbf(float a, float b) {
    unsigned ua = __float_as_uint(a);
    unsigned ub = __float_as_uint(b);
    ua = (ua + 0x7fffu + ((ua >> 16) & 1u)) >> 16;
    ub = (ub + 0x7fffu + ((ub >> 16) & 1u)) & 0xffff0000u;
    return ua | ub;
}

// Fused: X(fp32) -> Xb(bf16) convert  +  edge binning into ELL.
// All global streams here are single-use -> nt.
__global__ void setup_kernel(const float4* __restrict__ X4,
                             uint4* __restrict__ Xb,
                             const int* __restrict__ rows,
                             const int* __restrict__ cols,
                             const float* __restrict__ vals,
                             int* __restrict__ cnt,
                             int2* __restrict__ ell) {
    int tid = blockIdx.x * blockDim.x + threadIdx.x;
    if (tid < NCHUNK) {
        float4 a = ntload_f4(X4 + tid * 2);
        float4 b = ntload_f4(X4 + tid * 2 + 1);
        uint4 o;
        o.x = packbf(a.x, a.y);
        o.y = packbf(a.z, a.w);
        o.z = packbf(b.x, b.y);
        o.w = packbf(b.z, b.w);
        ntstore_u4(Xb + tid, o);
    }
    if (tid < N_EDGES) {
        int r = ntload_i(rows + tid);
        int slot = atomicAdd(&cnt[r], 1);
        if (slot < PAD) {
            int2 p;
            p.x = ntload_i(cols + tid);
            p.y = __float_as_int(ntload_f(vals + tid));
            ntstore_i2(ell + r * PAD + slot, p);
        }
    }
}

// One thread per (row, 16B chunk): 12 threads/row.
// FIRST: ego_in is Xb, acc is write-only (acc = X + ego1).
// LAST: skip ego_out store, fold /4 mean via scale.
// Gather loads stay cacheable; ELL/acc/ego_out are nt.
template <bool FIRST, bool LAST>
__global__ void spmm_fused_kernel(const uint4* __restrict__ ego_in,
                                  uint4* __restrict__ ego_out,
                                  const int* __restrict__ cnt,
                                  const int4* __restrict__ ell4,
                                  float4* __restrict__ acc,
                                  float scale) {
    int tid = blockIdx.x * blockDim.x + threadIdx.x;
    if (tid >= N_NODES * C16) return;
    int row = tid / C16;
    int ct  = tid % C16;

    int deg = cnt[row];
    if (deg > PAD) deg = PAD;
    const int4* ep = ell4 + row * (PAD / 2);

    // hoisted: independent of the gather chain
    int ib = row * C16 + ct;
    uint4 ea = ego_in[ib];
    int ia = row * (EMB / 4) + ct * 2;
    float4 a0, a1;
    if (!FIRST) {
        a0 = ntload_f4(acc + ia);
        a1 = ntload_f4(acc + ia + 1);
    }

    float s[8] = {0.f, 0.f, 0.f, 0.f, 0.f, 0.f, 0.f, 0.f};

    int j = 0;
    for (; j + 4 <= deg; j += 4) {
        int4 pA = ntload_i4(ep + (j >> 1) + 0);
        int4 pB = ntload_i4(ep + (j >> 1) + 1);
        uint4 x0 = ego_in[pA.x * C16 + ct];
        uint4 x1 = ego_in[pA.z * C16 + ct];
        uint4 x2 = ego_in[pB.x * C16 + ct];
        uint4 x3 = ego_in[pB.z * C16 + ct];
        fma_bf8(s, __int_as_float(pA.y), x0);
        fma_bf8(s, __int_as_float(pA.w), x1);
        fma_bf8(s, __int_as_float(pB.y), x2);
        fma_bf8(s, __int_as_float(pB.w), x3);
    }
    if (j + 2 <= deg) {
        int4 pA = ntload_i4(ep + (j >> 1));
        uint4 x0 = ego_in[pA.x * C16 + ct];
        uint4 x1 = ego_in[pA.z * C16 + ct];
        fma_bf8(s, __int_as_float(pA.y), x0);
        fma_bf8(s, __int_as_float(pA.w), x1);
        j += 2;
    }
    if (j < deg) {
        int2 p = ntload_i2((const int2*)ell4 + row * PAD + j);
        uint4 x0 = ego_in[p.x * C16 + ct];
        fma_bf8(s, __int_as_float(p.y), x0);
    }

    float e0[8] = {bflo(ea.x), bfhi(ea.x), bflo(ea.y), bfhi(ea.y),
                   bflo(ea.z), bfhi(ea.z), bflo(ea.w), bfhi(ea.w)};
    float n0[8];
#pragma unroll
    for (int k = 0; k < 8; ++k) n0[k] = fmaf(s[k], e0[k], s[k]);   // s*(1+e)

    if (!LAST) {
        uint4 oa;
        oa.x = packbf(n0[0], n0[1]); oa.y = packbf(n0[2], n0[3]);
        oa.z = packbf(n0[4], n0[5]); oa.w = packbf(n0[6], n0[7]);
        ntstore_u4(ego_out + ib, oa);
    }

    if (FIRST) {
        a0 = make_float4(e0[0] + n0[0], e0[1] + n0[1], e0[2] + n0[2], e0[3] + n0[3]);
        a1 = make_float4(e0[4] + n0[4], e0[5] + n0[5], e0[6] + n0[6], e0[7] + n0[7]);
    } else {
        a0.x = (a0.x + n0[0]) * scale; a0.y = (a0.y + n0[1]) * scale;
        a0.z = (a0.z + n0[2]) * scale; a0.w = (a0.w + n0[3]) * scale;
        a1.x = (a1.x + n0[4]) * scale; a1.y = (a1.y + n0[5]) * scale;
        a1.z = (a1.z + n0[6]) * scale; a1.w = (a1.w + n0[7]) * scale;
    }
    ntstore_f4(acc + ia,     a0);
    ntstore_f4(acc + ia + 1, a1);
}

extern "C" void kernel_launch(void* const* d_in, const int* in_sizes, int n_in,
                              void* d_out, int out_size, void* d_ws, size_t ws_size,
                              hipStream_t stream) {
    const float* X    = (const float*)d_in[0];
    const float* vals = (const float*)d_in[1];
    const int*   rows = (const int*)d_in[2];
    const int*   cols = (const int*)d_in[3];

    const size_t nodeb_bytes = (size_t)NCHUNK * sizeof(uint4);       // 9.6 MB
    const size_t ell_bytes   = (size_t)N_NODES * PAD * sizeof(int2); // 25.6 MB
    const size_t cnt_bytes   = (size_t)N_NODES * sizeof(int);

    float* acc = (float*)d_out;

    char* w = (char*)d_ws;
    uint4* Xb    = (uint4*)w;  w += nodeb_bytes;
    uint4* ego_a = (uint4*)w;  w += nodeb_bytes;
    uint4* ego_b = (uint4*)w;  w += nodeb_bytes;
    int2*  ell   = (int2*)w;   w += ell_bytes;
    int*   cnt   = (int*)w;

    hipMemsetAsync(cnt, 0, cnt_bytes, stream);
    setup_kernel<<<(N_EDGES + 255) / 256, 256, 0, stream>>>(
        (const float4*)X, Xb, rows, cols, vals, cnt, ell);

    const int blocks = (N_NODES * C16 + 255) / 256;
    const float last_scale = 1.0f / (LAYER_NUM + 1);

    spmm_fused_kernel<true, false><<<blocks, 256, 0, stream>>>(
        Xb, ego_a, cnt, (const int4*)ell, (float4*)acc, 1.0f);
    spmm_fused_kernel<false, false><<<blocks, 256, 0, stream>>>(
        ego_a, ego_b, cnt, (const int4*)ell, (float4*)acc, 1.0f);
    spmm_fused_kernel<false, true><<<blocks, 256, 0, stream>>>(
        ego_b, ego_a, cnt, (const int4*)ell, (float4*)acc, last_scale);
}